// Round 4
// baseline (865.435 us; speedup 1.0000x reference)
//
#include <hip/hip_runtime.h>

#define B_ 8
#define E_ 32768
#define N_ 4096
#define D_ 64
#define R_ 500
#define L_ 3
#define EPS_ 1e-5f

typedef short bf16x8 __attribute__((ext_vector_type(8)));
typedef float f32x4 __attribute__((ext_vector_type(4)));

__device__ __forceinline__ float sigm(float x){ return 1.0f/(1.0f + __expf(-x)); }
__device__ __forceinline__ unsigned short f2bf(float x){
  unsigned u = __float_as_uint(x);
  u += 0x7fffu + ((u>>16)&1u);
  return (unsigned short)(u>>16);
}

// fused prep: blocks [0,1500): statAdd; [1500,1503): w2sum; 1503: w1sum0; [1504,2012): betadot
__global__ void k_prep(const float* __restrict__ rel_table, const float* __restrict__ r_query,
                       const float* __restrict__ beta_w, const float* __restrict__ msg_w,
                       const float* __restrict__ msg_b,
                       float* __restrict__ statAdd, float* __restrict__ w2sum,
                       float* __restrict__ w1sum0, float* __restrict__ bdot,
                       float* __restrict__ qdot){
  int blk = blockIdx.x, j = threadIdx.x;   // 64 threads
  if(blk < L_*R_){
    int k = blk/R_, r = blk%R_;
    const float* W3 = msg_w + k*5*D_*D_ + 3*D_*D_;
    const float* rt = rel_table + r*D_;
    float s = msg_b[k*D_+j];
    #pragma unroll
    for(int i=0;i<D_;i++) s += rt[i]*W3[i*D_+j];
    statAdd[(k*R_+r)*D_+j] = s;
  } else if(blk < L_*R_+3){
    int k = blk - L_*R_;
    const float* W2 = msg_w + k*5*D_*D_ + 2*D_*D_;
    float s = 0.f;
    #pragma unroll
    for(int i=0;i<D_;i++) s += W2[i*D_+j];
    w2sum[k*D_+j] = s;
  } else if(blk == L_*R_+3){
    const float* W1 = msg_w + 1*D_*D_;     // layer-0 W1 block
    float s = 0.f;
    #pragma unroll
    for(int i=0;i<D_;i++) s += W1[i*D_+j];
    w1sum0[j] = s;
  } else {
    int item = blk - (L_*R_+4);
    if(item >= R_+B_) return;
    float x = (item < R_ ? rel_table[item*D_+j] : r_query[(item-R_)*D_+j]) * beta_w[j];
    #pragma unroll
    for(int off=32; off; off>>=1) x += __shfl_xor(x, off, 64);
    if(j==0){ if(item < R_) bdot[item] = x; else qdot[item-R_] = x; }
  }
}

// h init; hW1 (layer0) init; aggr zero
__global__ void k_init(float* __restrict__ h, float* __restrict__ aggr,
                       float* __restrict__ hW1, const float* __restrict__ w1sum0){
  int idx = blockIdx.x*256 + threadIdx.x;   // B*N*D
  int n = (idx / D_) & (N_-1);
  int j = idx & (D_-1);
  bool z = (n==0);
  h[idx]    = z ? 1.0f : 0.0f;
  hW1[idx]  = z ? w1sum0[j] : 0.0f;
  aggr[idx] = 0.0f;
}

// MFMA edge kernel: block = 256 threads = 4 waves = 256 edges.
// A[e][0:64]=h_src⊙h_r, A[e][64:128]=conf[e] (bf16 LDS, swizzle byte^=(row&7)<<4)
// B[kk][n] = kk<64?W0:W4, stored [n][kk]. D=A@B; epilogue via wave-private LDS round-trip.
__global__ void __launch_bounds__(256,2) k_edge(
    const int* __restrict__ edge_index, const int* __restrict__ rels,
    const float* __restrict__ scores, const int* __restrict__ confm,
    const float* __restrict__ bdot, const float* __restrict__ qdot,
    const float* __restrict__ beta_b,
    const float* __restrict__ h, const float* __restrict__ hW1,
    const float* __restrict__ rel_table, const float* __restrict__ conf,
    const float* __restrict__ msg_w, const float* __restrict__ statAdd,
    const float* __restrict__ w2sum, int k, float* __restrict__ aggr){
  __shared__ __align__(16) unsigned short Ash[256*128];   // 64 KB (reused as f32 scratch)
  __shared__ __align__(16) unsigned short Bsh[64*128];    // 16 KB

  const int tid  = threadIdx.x;
  const int wid  = tid >> 6;
  const int lane = tid & 63;
  const int blk  = blockIdx.x;
  const int b    = blk >> 7;                 // 128 blocks per batch
  const int ebase = blk*256 + wid*64;

  // per-lane edge metadata + inline gate
  const int eg  = ebase + lane;
  const int ein = eg & (E_-1);
  int   srcv = edge_index[b*2*E_ + ein];
  int   tgtv = edge_index[b*2*E_ + E_ + ein];
  int   relv = rels[eg];
  float beta = sigm(bdot[relv] + qdot[b] + beta_b[0]);
  float gv   = (confm[eg] != 0) ? sigm((scores[eg]-beta)*10.0f) : 0.5f;

  // --- B staging: float4 coalesced loads, transposed swizzled ushort writes ---
  {
    const float* W0 = msg_w + k*5*D_*D_;
    #pragma unroll
    for(int it=0; it<8; it++){
      int q  = it*256 + tid;                 // quad index over 128x64 / 4
      int kk = q >> 4;
      int n4 = (q & 15)*4;
      float4 v = *(const float4*)(W0 + (kk<64 ? kk*64+n4 : 4*D_*D_ + (kk-64)*64+n4));
      int kb = kk*2;
      #pragma unroll
      for(int c=0;c<4;c++){
        int n = n4 + c;
        float vc = (c==0)?v.x:(c==1)?v.y:(c==2)?v.z:v.w;
        *(unsigned short*)((char*)Bsh + n*256 + (kb ^ ((n&7)<<4))) = f2bf(vc);
      }
    }
  }
  // --- A staging p-half: 4 rows/instr, float4 gathers of h & rel_table ---
  #pragma unroll
  for(int t=0;t<16;t++){
    int i   = t*4 + (lane>>4);               // wave-local edge row
    int s_i = __shfl(srcv, i);
    int r_i = __shfl(relv, i);
    float4 hv = *(const float4*)(h + (size_t)(b*N_+s_i)*64 + (lane&15)*4);
    float4 rv = *(const float4*)(rel_table + (size_t)r_i*64 + (lane&15)*4);
    int row = wid*64 + i;
    unsigned p0 = (unsigned)f2bf(hv.x*rv.x) | ((unsigned)f2bf(hv.y*rv.y)<<16);
    unsigned p1 = (unsigned)f2bf(hv.z*rv.z) | ((unsigned)f2bf(hv.w*rv.w)<<16);
    char* p = (char*)Ash + row*256 + (((lane&15)*8) ^ ((row&7)<<4));
    *(unsigned*)p = p0; *(unsigned*)(p+4) = p1;
  }
  // --- A staging conf-half: contiguous float4 stream ---
  {
    const float* cb = conf + (size_t)ebase*64;
    #pragma unroll
    for(int t=0;t<16;t++){
      float4 cv = *(const float4*)(cb + t*256 + lane*4);
      int row = wid*64 + t*4 + (lane>>4);
      unsigned p0 = (unsigned)f2bf(cv.x) | ((unsigned)f2bf(cv.y)<<16);
      unsigned p1 = (unsigned)f2bf(cv.z) | ((unsigned)f2bf(cv.w)<<16);
      char* p = (char*)Ash + row*256 + 128 + (((lane&15)*8) ^ ((row&7)<<4));
      *(unsigned*)p = p0; *(unsigned*)(p+4) = p1;
    }
  }
  __syncthreads();

  // --- MFMA: 64 edges x 64 outputs x K=128 ---
  f32x4 acc[4][4];
  #pragma unroll
  for(int mt=0;mt<4;mt++)
    #pragma unroll
    for(int nt=0;nt<4;nt++) acc[mt][nt] = (f32x4){0.f,0.f,0.f,0.f};

  #pragma unroll
  for(int kt=0;kt<4;kt++){
    bf16x8 af[4], bfr[4];
    int kbyte = kt*64 + ((lane>>4)*16);
    #pragma unroll
    for(int mt=0;mt<4;mt++){
      int row = wid*64 + mt*16 + (lane&15);
      af[mt] = *(const bf16x8*)((const char*)Ash + row*256 + (kbyte ^ ((row&7)<<4)));
    }
    #pragma unroll
    for(int nt=0;nt<4;nt++){
      int n = nt*16 + (lane&15);
      bfr[nt] = *(const bf16x8*)((const char*)Bsh + n*256 + (kbyte ^ ((n&7)<<4)));
    }
    #pragma unroll
    for(int mt=0;mt<4;mt++)
      #pragma unroll
      for(int nt=0;nt<4;nt++)
        acc[mt][nt] = __builtin_amdgcn_mfma_f32_16x16x32_bf16(af[mt], bfr[nt], acc[mt][nt], 0,0,0);
  }

  // --- epilogue: acc -> wave-private LDS (f32) -> row-major float4 processing ---
  char* Fb = (char*)Ash + wid*16384;         // 64 rows x 256B, wave-private (was our A rows)
  #pragma unroll
  for(int mt=0;mt<4;mt++)
    #pragma unroll
    for(int nt=0;nt<4;nt++){
      int colb = (nt*16 + (lane&15))*4;
      #pragma unroll
      for(int jr=0;jr<4;jr++){
        int row = mt*16 + (lane>>4)*4 + jr;
        *(float*)(Fb + row*256 + (colb ^ ((row&7)<<4))) = acc[mt][nt][jr];
      }
    }
  // DS queue is in-order per wave; region is wave-private -> no barrier needed
  const float* w2 = w2sum + k*64;
  #pragma unroll
  for(int t=0;t<16;t++){
    int i   = t*4 + (lane>>4);
    int s_i = __shfl(srcv, i);
    int tg  = __shfl(tgtv, i);
    int r_i = __shfl(relv, i);
    float g_i = __shfl(gv, i);
    f32x4 fv = *(const f32x4*)(Fb + i*256 + (((lane&15)*16) ^ ((i&7)<<4)));
    f32x4 sa = *(const f32x4*)(statAdd + (size_t)(k*R_+r_i)*64 + (lane&15)*4);
    f32x4 hw = *(const f32x4*)(hW1 + (size_t)(b*N_+s_i)*64 + (lane&15)*4);
    f32x4 wv = *(const f32x4*)(w2 + (lane&15)*4);
    float is0 = (s_i==0) ? 1.0f : 0.0f;
    float* ar = aggr + (size_t)(b*N_+tg)*64 + (lane&15)*4;
    #pragma unroll
    for(int c=0;c<4;c++){
      float v = fv[c] + sa[c] + hw[c] + is0*wv[c];
      v = fmaxf(v, 0.f) * g_i;
      unsafeAtomicAdd(ar+c, v);
    }
  }
}

// h = LN(h + aggr@U_k + b); aggr = 0; hW1 = h@W1_{k+1} (if k<L-1); ctx out for node 0
__global__ void k_update(float* __restrict__ aggr, const float* __restrict__ upd_w,
                         const float* __restrict__ upd_b, const float* __restrict__ ln_g,
                         const float* __restrict__ ln_b, const float* __restrict__ msg_w,
                         int k, float* __restrict__ h, float* __restrict__ hW1,
                         float* __restrict__ out){
  int node = blockIdx.x*4 + (threadIdx.x>>6);
  int j = threadIdx.x & 63;
  int b = node >> 12;
  int n = node & (N_-1);
  size_t idx = (size_t)node*64 + j;
  const float* U = upd_w + k*D_*D_;
  float a = aggr[idx];
  aggr[idx] = 0.0f;                          // cleared for next layer / next launch
  float acc = h[idx] + upd_b[k*D_+j];
  #pragma unroll
  for(int i=0;i<D_;i++) acc += __shfl(a, i, 64) * U[i*D_+j];
  float s = acc, sq = acc*acc;
  #pragma unroll
  for(int off=32; off; off>>=1){
    s  += __shfl_xor(s,  off, 64);
    sq += __shfl_xor(sq, off, 64);
  }
  float mean = s * (1.0f/64.0f);
  float var  = sq * (1.0f/64.0f) - mean*mean;
  float y = (acc - mean)*rsqrtf(var + EPS_)*ln_g[j] + ln_b[j];
  h[idx] = y;
  if(n==0) out[(b*L_+k)*D_+j] = y;
  if(k < L_-1){
    const float* W1 = msg_w + (k+1)*5*D_*D_ + D_*D_;
    float w = 0.f;
    #pragma unroll
    for(int i=0;i<D_;i++) w += __shfl(y, i, 64) * W1[i*D_+j];
    hW1[idx] = w;
  }
}

extern "C" void kernel_launch(void* const* d_in, const int* in_sizes, int n_in,
                              void* d_out, int out_size, void* d_ws, size_t ws_size,
                              hipStream_t stream) {
  const int*   edge_index = (const int*)d_in[0];
  const int*   rels       = (const int*)d_in[1];
  const float* scores     = (const float*)d_in[2];
  const int*   confm      = (const int*)d_in[3];
  const float* r_query    = (const float*)d_in[6];
  const float* rel_table  = (const float*)d_in[7];
  const float* conf       = (const float*)d_in[8];
  const float* beta_w     = (const float*)d_in[9];
  const float* beta_b     = (const float*)d_in[10];
  const float* msg_w      = (const float*)d_in[11];
  const float* msg_b      = (const float*)d_in[12];
  const float* upd_w      = (const float*)d_in[13];
  const float* upd_b      = (const float*)d_in[14];
  const float* ln_g       = (const float*)d_in[15];
  const float* ln_b       = (const float*)d_in[16];
  float* out = (float*)d_out;

  float* ws      = (float*)d_ws;
  float* h       = ws;                        // B*N*D
  float* aggr    = h    + B_*N_*D_;           // B*N*D
  float* hW1     = aggr + B_*N_*D_;           // B*N*D
  float* statAdd = hW1  + B_*N_*D_;           // L*R*D
  float* w2sum   = statAdd + L_*R_*D_;        // L*D
  float* w1sum0  = w2sum + L_*D_;             // D
  float* bdot    = w1sum0 + D_;               // 512 (padded)
  float* qdot    = bdot + 512;                // B

  k_prep<<<L_*R_+4+R_+B_, 64, 0, stream>>>(rel_table, r_query, beta_w, msg_w, msg_b,
                                           statAdd, w2sum, w1sum0, bdot, qdot);
  k_init<<<(B_*N_*D_)/256, 256, 0, stream>>>(h, aggr, hW1, w1sum0);

  for(int k=0;k<L_;k++){
    k_edge<<<(B_*E_)/256, 256, 0, stream>>>(edge_index, rels, scores, confm, bdot, qdot,
                                            beta_b, h, hW1, rel_table, conf, msg_w,
                                            statAdd, w2sum, k, aggr);
    k_update<<<(B_*N_)/4, 256, 0, stream>>>(aggr, upd_w, upd_b, ln_g, ln_b, msg_w,
                                            k, h, hW1, out);
  }
}

// Round 5
// 428.524 us; speedup vs baseline: 2.0196x; 2.0196x over previous
//
#include <hip/hip_runtime.h>

#define B_ 8
#define E_ 32768
#define N_ 4096
#define D_ 64
#define R_ 500
#define L_ 3
#define EPS_ 1e-5f

typedef short bf16x8 __attribute__((ext_vector_type(8)));
typedef float f32x4 __attribute__((ext_vector_type(4)));

__device__ __forceinline__ float sigm(float x){ return 1.0f/(1.0f + __expf(-x)); }
__device__ __forceinline__ unsigned short f2bf(float x){
  unsigned u = __float_as_uint(x);
  u += 0x7fffu + ((u>>16)&1u);
  return (unsigned short)(u>>16);
}

// fused prep: blocks [0,1500): statAdd; [1500,1503): w2sum; 1503: w1sum0; [1504,2012): betadot
__global__ void k_prep(const float* __restrict__ rel_table, const float* __restrict__ r_query,
                       const float* __restrict__ beta_w, const float* __restrict__ msg_w,
                       const float* __restrict__ msg_b,
                       float* __restrict__ statAdd, float* __restrict__ w2sum,
                       float* __restrict__ w1sum0, float* __restrict__ bdot,
                       float* __restrict__ qdot){
  int blk = blockIdx.x, j = threadIdx.x;   // 64 threads
  if(blk < L_*R_){
    int k = blk/R_, r = blk%R_;
    const float* W3 = msg_w + k*5*D_*D_ + 3*D_*D_;
    const float* rt = rel_table + r*D_;
    float s = msg_b[k*D_+j];
    #pragma unroll
    for(int i=0;i<D_;i++) s += rt[i]*W3[i*D_+j];
    statAdd[(k*R_+r)*D_+j] = s;
  } else if(blk < L_*R_+3){
    int k = blk - L_*R_;
    const float* W2 = msg_w + k*5*D_*D_ + 2*D_*D_;
    float s = 0.f;
    #pragma unroll
    for(int i=0;i<D_;i++) s += W2[i*D_+j];
    w2sum[k*D_+j] = s;
  } else if(blk == L_*R_+3){
    const float* W1 = msg_w + 1*D_*D_;     // layer-0 W1 block
    float s = 0.f;
    #pragma unroll
    for(int i=0;i<D_;i++) s += W1[i*D_+j];
    w1sum0[j] = s;
  } else {
    int item = blk - (L_*R_+4);
    if(item >= R_+B_) return;
    float x = (item < R_ ? rel_table[item*D_+j] : r_query[(item-R_)*D_+j]) * beta_w[j];
    #pragma unroll
    for(int off=32; off; off>>=1) x += __shfl_xor(x, off, 64);
    if(j==0){ if(item < R_) bdot[item] = x; else qdot[item-R_] = x; }
  }
}

// h init; hW1' (layer0, w2sum folded) init; aggr zero
__global__ void k_init(float* __restrict__ h, float* __restrict__ aggr,
                       float* __restrict__ hW1, const float* __restrict__ w1sum0,
                       const float* __restrict__ w2sum){
  int idx = blockIdx.x*256 + threadIdx.x;   // B*N*D
  int n = (idx / D_) & (N_-1);
  int j = idx & (D_-1);
  bool z = (n==0);
  h[idx]    = z ? 1.0f : 0.0f;
  hW1[idx]  = z ? (w1sum0[j] + w2sum[j]) : 0.0f;   // w2sum of layer 0
  aggr[idx] = 0.0f;
}

// MFMA edge kernel: block = 256 threads = 4 waves = 256 edges.
// GEMM1: A=p (h_src⊙h_r) in LDS (bf16, 32KB, swizzled) x W0.  K=64
// GEMM2: A=conf fragments DIRECT from global (f32->bf16 in regs) x W4.  K=64
// Bsh[n][0:64]=W0, [64:128]=W4 transposed.  Epilogue: line-grouped atomics (R2 pattern).
__global__ void __launch_bounds__(256,3) k_edge(
    const int* __restrict__ edge_index, const int* __restrict__ rels,
    const float* __restrict__ scores, const int* __restrict__ confm,
    const float* __restrict__ bdot, const float* __restrict__ qdot,
    const float* __restrict__ beta_b,
    const float* __restrict__ h, const float* __restrict__ hW1,
    const float* __restrict__ rel_table, const float* __restrict__ conf,
    const float* __restrict__ msg_w, const float* __restrict__ statAdd,
    int k, float* __restrict__ aggr){
  __shared__ __align__(16) unsigned short Ash[256*64];    // 32 KB  (p-half only, 128B rows)
  __shared__ __align__(16) unsigned short Bsh[64*128];    // 16 KB

  const int tid  = threadIdx.x;
  const int wid  = tid >> 6;
  const int lane = tid & 63;
  const int blk  = blockIdx.x;
  const int b    = blk >> 7;                 // 128 blocks per batch
  const int ebase = blk*256 + wid*64;

  // per-lane edge metadata + inline gate
  const int eg  = ebase + lane;
  const int ein = eg & (E_-1);
  int   srcv = edge_index[b*2*E_ + ein];
  int   tgtv = edge_index[b*2*E_ + E_ + ein];
  int   relv = rels[eg];
  float beta = sigm(bdot[relv] + qdot[b] + beta_b[0]);
  float gv   = (confm[eg] != 0) ? sigm((scores[eg]-beta)*10.0f) : 0.5f;

  // --- B staging: float4 coalesced loads, transposed swizzled ushort writes ---
  {
    const float* W0 = msg_w + k*5*D_*D_;
    #pragma unroll
    for(int it=0; it<8; it++){
      int q  = it*256 + tid;                 // quad over 128k x 16 n-quads
      int kk = q >> 4;
      int n4 = (q & 15)*4;
      float4 v = *(const float4*)(W0 + (kk<64 ? kk*64+n4 : 4*D_*D_ + (kk-64)*64+n4));
      int kb = kk*2;
      #pragma unroll
      for(int c=0;c<4;c++){
        int n = n4 + c;
        float vc = (c==0)?v.x:(c==1)?v.y:(c==2)?v.z:v.w;
        *(unsigned short*)((char*)Bsh + n*256 + (kb ^ ((n&7)<<4))) = f2bf(vc);
      }
    }
  }
  // --- A staging p-half: 4 rows/instr, float4 gathers of h & rel_table ---
  #pragma unroll
  for(int t=0;t<16;t++){
    int i   = t*4 + (lane>>4);               // wave-local edge row
    int s_i = __shfl(srcv, i);
    int r_i = __shfl(relv, i);
    float4 hv = *(const float4*)(h + (size_t)(b*N_+s_i)*64 + (lane&15)*4);
    float4 rv = *(const float4*)(rel_table + (size_t)r_i*64 + (lane&15)*4);
    int row = wid*64 + i;
    unsigned p0 = (unsigned)f2bf(hv.x*rv.x) | ((unsigned)f2bf(hv.y*rv.y)<<16);
    unsigned p1 = (unsigned)f2bf(hv.z*rv.z) | ((unsigned)f2bf(hv.w*rv.w)<<16);
    char* p = (char*)Ash + row*128 + (((lane&15)*8) ^ ((row&7)<<4));
    *(unsigned*)p = p0; *(unsigned*)(p+4) = p1;
  }
  // --- conf A-fragments: direct global load (MFMA layout), f32->bf16 in regs ---
  bf16x8 af2[4][2];
  {
    const float* cb = conf + (size_t)ebase*64;
    #pragma unroll
    for(int mt=0;mt<4;mt++){
      #pragma unroll
      for(int kt2=0;kt2<2;kt2++){
        const float* src = cb + (size_t)(mt*16 + (lane&15))*64 + kt2*32 + (lane>>4)*8;
        float4 u0 = *(const float4*)(src);
        float4 u1 = *(const float4*)(src+4);
        bf16x8 v;
        v[0]=(short)f2bf(u0.x); v[1]=(short)f2bf(u0.y); v[2]=(short)f2bf(u0.z); v[3]=(short)f2bf(u0.w);
        v[4]=(short)f2bf(u1.x); v[5]=(short)f2bf(u1.y); v[6]=(short)f2bf(u1.z); v[7]=(short)f2bf(u1.w);
        af2[mt][kt2] = v;
      }
    }
  }
  __syncthreads();

  // --- MFMA: 64 edges x 64 outputs, K=64 (p@W0) + K=64 (conf@W4) ---
  f32x4 acc[4][4];
  #pragma unroll
  for(int mt=0;mt<4;mt++)
    #pragma unroll
    for(int nt=0;nt<4;nt++) acc[mt][nt] = (f32x4){0.f,0.f,0.f,0.f};

  #pragma unroll
  for(int kt=0;kt<2;kt++){                   // p @ W0
    bf16x8 af[4], bfr[4];
    int kbyte = kt*64 + ((lane>>4)*16);
    #pragma unroll
    for(int mt=0;mt<4;mt++){
      int row = wid*64 + mt*16 + (lane&15);
      af[mt] = *(const bf16x8*)((const char*)Ash + row*128 + (kbyte ^ ((row&7)<<4)));
    }
    #pragma unroll
    for(int nt=0;nt<4;nt++){
      int n = nt*16 + (lane&15);
      bfr[nt] = *(const bf16x8*)((const char*)Bsh + n*256 + (kbyte ^ ((n&7)<<4)));
    }
    #pragma unroll
    for(int mt=0;mt<4;mt++)
      #pragma unroll
      for(int nt=0;nt<4;nt++)
        acc[mt][nt] = __builtin_amdgcn_mfma_f32_16x16x32_bf16(af[mt], bfr[nt], acc[mt][nt], 0,0,0);
  }
  #pragma unroll
  for(int kt2=0;kt2<2;kt2++){                // conf @ W4 (A from registers)
    bf16x8 bfr[4];
    int kbyte = 128 + kt2*64 + ((lane>>4)*16);
    #pragma unroll
    for(int nt=0;nt<4;nt++){
      int n = nt*16 + (lane&15);
      bfr[nt] = *(const bf16x8*)((const char*)Bsh + n*256 + (kbyte ^ ((n&7)<<4)));
    }
    #pragma unroll
    for(int mt=0;mt<4;mt++)
      #pragma unroll
      for(int nt=0;nt<4;nt++)
        acc[mt][nt] = __builtin_amdgcn_mfma_f32_16x16x32_bf16(af2[mt][kt2], bfr[nt], acc[mt][nt], 0,0,0);
  }

  // --- epilogue: R2 pattern — one 64B line per 16-lane group per atomic instr ---
  #pragma unroll
  for(int mt=0;mt<4;mt++){
    #pragma unroll
    for(int jr=0;jr<4;jr++){
      int eloc  = mt*16 + (lane>>4)*4 + jr;
      int tgt_e = __shfl(tgtv, eloc);
      int src_e = __shfl(srcv, eloc);
      int r_e   = __shfl(relv, eloc);
      float g_e = __shfl(gv,   eloc);
      const float* sa = statAdd + (size_t)(k*R_ + r_e)*64;
      const float* hw = hW1 + (size_t)(b*N_ + src_e)*64;
      float* ar = aggr + (size_t)(b*N_ + tgt_e)*64;
      #pragma unroll
      for(int nt=0;nt<4;nt++){
        int j = nt*16 + (lane&15);
        float v = acc[mt][nt][jr] + sa[j] + hw[j];
        v = fmaxf(v, 0.f) * g_e;
        unsafeAtomicAdd(ar + j, v);
      }
    }
  }
}

// h = LN(h + aggr@U_k + b); aggr = 0; hW1' = h@W1_{k+1} + (n==0)*w2sum_{k+1}; ctx out
__global__ void k_update(float* __restrict__ aggr, const float* __restrict__ upd_w,
                         const float* __restrict__ upd_b, const float* __restrict__ ln_g,
                         const float* __restrict__ ln_b, const float* __restrict__ msg_w,
                         const float* __restrict__ w2sum, int k,
                         float* __restrict__ h, float* __restrict__ hW1,
                         float* __restrict__ out){
  int node = blockIdx.x*4 + (threadIdx.x>>6);
  int j = threadIdx.x & 63;
  int b = node >> 12;
  int n = node & (N_-1);
  size_t idx = (size_t)node*64 + j;
  const float* U = upd_w + k*D_*D_;
  float a = aggr[idx];
  aggr[idx] = 0.0f;                          // cleared for next layer / next launch
  // 4-way split accumulation (breaks 64-deep dependent FMA chain)
  float c0 = h[idx] + upd_b[k*D_+j], c1 = 0.f, c2 = 0.f, c3 = 0.f;
  #pragma unroll
  for(int i=0;i<16;i++){
    c0 += __shfl(a, i,      64) * U[(i)*D_+j];
    c1 += __shfl(a, i+16,   64) * U[(i+16)*D_+j];
    c2 += __shfl(a, i+32,   64) * U[(i+32)*D_+j];
    c3 += __shfl(a, i+48,   64) * U[(i+48)*D_+j];
  }
  float acc = (c0+c1)+(c2+c3);
  float s = acc, sq = acc*acc;
  #pragma unroll
  for(int off=32; off; off>>=1){
    s  += __shfl_xor(s,  off, 64);
    sq += __shfl_xor(sq, off, 64);
  }
  float mean = s * (1.0f/64.0f);
  float var  = sq * (1.0f/64.0f) - mean*mean;
  float y = (acc - mean)*rsqrtf(var + EPS_)*ln_g[j] + ln_b[j];
  h[idx] = y;
  if(n==0) out[(b*L_+k)*D_+j] = y;
  if(k < L_-1){
    const float* W1 = msg_w + (k+1)*5*D_*D_ + D_*D_;
    float w0 = 0.f, w1 = 0.f, w2 = 0.f, w3 = 0.f;
    #pragma unroll
    for(int i=0;i<16;i++){
      w0 += __shfl(y, i,    64) * W1[(i)*D_+j];
      w1 += __shfl(y, i+16, 64) * W1[(i+16)*D_+j];
      w2 += __shfl(y, i+32, 64) * W1[(i+32)*D_+j];
      w3 += __shfl(y, i+48, 64) * W1[(i+48)*D_+j];
    }
    hW1[idx] = (w0+w1)+(w2+w3) + ((n==0) ? w2sum[(k+1)*D_+j] : 0.0f);
  }
}

extern "C" void kernel_launch(void* const* d_in, const int* in_sizes, int n_in,
                              void* d_out, int out_size, void* d_ws, size_t ws_size,
                              hipStream_t stream) {
  const int*   edge_index = (const int*)d_in[0];
  const int*   rels       = (const int*)d_in[1];
  const float* scores     = (const float*)d_in[2];
  const int*   confm      = (const int*)d_in[3];
  const float* r_query    = (const float*)d_in[6];
  const float* rel_table  = (const float*)d_in[7];
  const float* conf       = (const float*)d_in[8];
  const float* beta_w     = (const float*)d_in[9];
  const float* beta_b     = (const float*)d_in[10];
  const float* msg_w      = (const float*)d_in[11];
  const float* msg_b      = (const float*)d_in[12];
  const float* upd_w      = (const float*)d_in[13];
  const float* upd_b      = (const float*)d_in[14];
  const float* ln_g       = (const float*)d_in[15];
  const float* ln_b       = (const float*)d_in[16];
  float* out = (float*)d_out;

  float* ws      = (float*)d_ws;
  float* h       = ws;                        // B*N*D
  float* aggr    = h    + B_*N_*D_;           // B*N*D
  float* hW1     = aggr + B_*N_*D_;           // B*N*D
  float* statAdd = hW1  + B_*N_*D_;           // L*R*D
  float* w2sum   = statAdd + L_*R_*D_;        // L*D
  float* w1sum0  = w2sum + L_*D_;             // D
  float* bdot    = w1sum0 + D_;               // 512 (padded)
  float* qdot    = bdot + 512;                // B

  k_prep<<<L_*R_+4+R_+B_, 64, 0, stream>>>(rel_table, r_query, beta_w, msg_w, msg_b,
                                           statAdd, w2sum, w1sum0, bdot, qdot);
  k_init<<<(B_*N_*D_)/256, 256, 0, stream>>>(h, aggr, hW1, w1sum0, w2sum);

  for(int k=0;k<L_;k++){
    k_edge<<<(B_*E_)/256, 256, 0, stream>>>(edge_index, rels, scores, confm, bdot, qdot,
                                            beta_b, h, hW1, rel_table, conf, msg_w,
                                            statAdd, k, aggr);
    k_update<<<(B_*N_)/4, 256, 0, stream>>>(aggr, upd_w, upd_b, ln_g, ln_b, msg_w,
                                            w2sum, k, h, hW1, out);
  }
}